// Round 8
// baseline (136.137 us; speedup 1.0000x reference)
//
#include <hip/hip_runtime.h>
#include <math.h>

#define S_LEN  4096
#define NCH    64
#define TILE_S 64
#define RPT    8           // s-rows per thread
#define TY     8           // 512 threads = 8 waves
#define NROWS  128         // staged rows (64 tile + 64 halo), row-major, no pad
#define WLEN   70          // win floats; used indices 1..69

// ---------------------------------------------------------------------------
// Round-11 = Round-10 with the staging index bug fixed. R7 FAILED (absmax 624)
// because the float4 slot decode used row=slot>>2,q=slot&3 — but a 64-float
// row has 16 float4 slots, not 4. LDS writes went out of bounds (row up to
// 511 vs 128) and only channels 0..15 were read. Fix: row=slot>>4, q=slot&15
// (as in the validated R0 stage). NOTHING else changed — this round actually
// tests the phase-convoy theory:
//   Six rounds of scheduling/occupancy/weight changes all land 46-53us vs
//   ~24us memory floor (VALUBusy ~34%, HBM ~3TB/s: neither pipe saturated).
//   Model: bulk-sync co-resident blocks phase-lock -> chip-wide passes of
//   {read | compute | store}; time = SUM of phases. Fix: PER-ROW COMPLETION -
//   all 106 taps of row R into 3 scalar accs, store row R's 3 outputs
//   immediately, then R+1. Store stream spreads across the compute phase
//   (pass -> read + max(compute,store)); block finish times spread -> reads
//   stagger too.
// Stage: row-major LDS, float4 both sides; window reads 69 ds_read_b32,
// bank = c%32 -> 2 lanes/bank = free (m136). Kept: constexpr literal weights
// (R4 win), XCD swizzle. RPT=8, TILE_S=64.
// ---------------------------------------------------------------------------

// ---- constexpr weight construction (compile-time) --------------------------
constexpr double cexp_(double v) {            // v in [-25, 0]
  const double LN2 = 0.6931471805599453;
  double t = v / LN2;
  int k = (int)t;
  if (t < 0.0 && (double)k != t) --k;
  double r = v - (double)k * LN2;             // r in [0, ln2)
  double term = 1.0, sum = 1.0;
  for (int n = 1; n <= 22; ++n) { term *= r / (double)n; sum += term; }
  while (k > 0) { sum *= 2.0; --k; }
  while (k < 0) { sum *= 0.5; ++k; }
  return sum;
}
constexpr double csqrt_(double a) {
  double y = a > 1.0 ? a : 1.0;
  for (int i = 0; i < 64; ++i) y = 0.5 * (y + a / y);
  return y;
}
struct Wt { float w6[62]; float w3[32]; float w1[12]; };
constexpr Wt make_weights() {
  Wt w{};
  double ip[1024] = {};
  const double delta = 10.0 / 1023.0;
  const double step  = (-5.0 + delta) + 5.0;        // == numpy x[1]-x[0]
  const double cn    = csqrt_(csqrt_(1.5707963267948966)); // (pi/2)^0.25
  double s = 0.0;
  for (int i = 0; i < 1024; ++i) {
    const double xi  = (i == 1023) ? 5.0 : ((double)i * delta - 5.0);
    const double psi = (-2.0 * xi) * cexp_(-(xi * xi)) / cn;
    s += psi;
    ip[i] = s * step;
  }
  const int as_[3] = {6, 3, 1};
  const int lf_[3] = {61, 31, 11};
  for (int si = 0; si < 3; ++si) {
    const double denom = (double)as_[si] * step;
    const float  sqa   = (float)csqrt_((double)as_[si]);
    const int    lf    = lf_[si];
    for (int t = 0; t <= lf; ++t) {
      float km1 = 0.f, kt = 0.f;
      if (t >= 1)      km1 = (float)ip[(long)(((double)(t - 1)) / denom)];
      if (t <= lf - 1) kt  = (float)ip[(long)(((double)t) / denom)];
      const float val = -sqa * (km1 - kt);
      if (si == 0) w.w6[t] = val; else if (si == 1) w.w3[t] = val; else w.w1[t] = val;
    }
  }
  return w;
}
constexpr Wt CW = make_weights();
// Template variables force compile-time folding -> inline literal operands.
template <int T> constexpr float W6 = CW.w6[T];
template <int T> constexpr float W3 = CW.w3[T];
template <int T> constexpr float W1 = CW.w1[T];

// ---- preload window rows 1..62 from row-major LDS (stride NCH dwords) ------
template <int K>
struct PreW {
  static __device__ __forceinline__ void run(const float* __restrict__ colbase,
                                             float (&win)[WLEN]) {
    win[K] = colbase[K * NCH];
    PreW<K + 1>::run(colbase, win);
  }
};
template <>
struct PreW<63> {
  static __device__ __forceinline__ void run(const float* __restrict__, float (&)[WLEN]) {}
};

// ---- per-row tap chain (3 scalar accumulators), all indices compile-time ---
template <int R, int T>
struct Tap {
  static __device__ __forceinline__ void run(const float (&win)[WLEN], float& a6,
                                             float& a3, float& a1) {
    a6 = fmaf(W6<T>, win[T + R + 1], a6);
    if constexpr (T >= 15 && T <= 46) a3 = fmaf(W3<T - 15>, win[T + R + 1], a3);
    if constexpr (T >= 25 && T <= 36) a1 = fmaf(W1<T - 25>, win[T + R + 1], a1);
    Tap<R, T + 1>::run(win, a6, a3, a1);
  }
};
template <int R>
struct Tap<R, 62> {
  static __device__ __forceinline__ void run(const float (&)[WLEN], float&, float&, float&) {}
};

// ---- per-row: load 1 new window value, run taps, store 3 outputs -----------
template <int R>
struct Row {
  static __device__ __forceinline__ void run(const float* __restrict__ colbase,
                                             float (&win)[WLEN], float* __restrict__ o1,
                                             float* __restrict__ o3, float* __restrict__ o6) {
    if constexpr (R > 0) win[R + 62] = colbase[(R + 62) * NCH];
    float a6 = 0.f, a3 = 0.f, a1 = 0.f;
    Tap<R, 0>::run(win, a6, a3, a1);
    o1[(size_t)R * NCH] = a1;                 // stores interleave with compute
    o3[(size_t)R * NCH] = a3;
    o6[(size_t)R * NCH] = a6;
    Row<R + 1>::run(colbase, win, o1, o3, o6);
  }
};
template <>
struct Row<RPT> {
  static __device__ __forceinline__ void run(const float* __restrict__, float (&)[WLEN],
                                             float* __restrict__, float* __restrict__,
                                             float* __restrict__) {}
};

__global__ __launch_bounds__(512, 6)
void cwt_main(const float* __restrict__ x, float* __restrict__ out) {
  __shared__ __align__(16) float lds[NROWS * NCH];   // 32768 B, row-major, no pad

  const int c  = threadIdx.x;         // 0..63 (lane = channel)
  const int ty = threadIdx.y;         // 0..7 (wave)
  const int tid = ty * 64 + c;

  // Bijective XCD swizzle (2048 % 8 == 0): 256 consecutive logical blocks per
  // XCD; consecutive sx tiles share 64 halo rows -> same-XCD L2 hits.
  const int hw = blockIdx.x;                  // 0..2047
  const int wg = ((hw & 7) << 8) + (hw >> 3);
  const int sx = wg & 63;                     // 64 s-tiles (fastest within XCD)
  const int b  = wg >> 6;                     // 32 signals
  const int s0 = sx * TILE_S;
  const int ROW0 = s0 - 32;                   // staged rows (quad-aligned halo)

  const float* __restrict__ xb = x + (size_t)b * S_LEN * NCH;

  // ---- stage 128 rows row-major: 16 float4 slots PER ROW (64 floats).
  // 2048 slots total; 4 per thread; both sides coalesced; zero-fill OOB.
  #pragma unroll
  for (int i = 0; i < 4; ++i) {
    const int slot = tid + i * 512;           // 0..2047
    const int row  = slot >> 4, q = slot & 15;   // FIXED: 16 slots/row
    const int grow = ROW0 + row;
    float4 v = make_float4(0.f, 0.f, 0.f, 0.f);
    if ((unsigned)grow < (unsigned)S_LEN)
      v = *(const float4*)(xb + ((size_t)grow * NCH + (q << 2)));
    *(float4*)&lds[row * NCH + (q << 2)] = v;
  }
  __syncthreads();

  // ---- per-row compute + store; window reads ds_read_b32, 2-way-free banks
  const float* __restrict__ colbase = &lds[(RPT * ty) * NCH + c];

  float win[WLEN];
  PreW<1>::run(colbase, win);                 // win[1..62]

  const int srow = s0 + RPT * ty;
  float* o1 = out + (((size_t)b * 3 + 0) * S_LEN + srow) * NCH + c;
  float* o3 = out + (((size_t)b * 3 + 1) * S_LEN + srow) * NCH + c;
  float* o6 = out + (((size_t)b * 3 + 2) * S_LEN + srow) * NCH + c;

  Row<0>::run(colbase, win, o1, o3, o6);      // rows 0..7: taps + immediate store
}

extern "C" void kernel_launch(void* const* d_in, const int* in_sizes, int n_in,
                              void* d_out, int out_size, void* d_ws, size_t ws_size,
                              hipStream_t stream) {
  (void)n_in; (void)out_size; (void)d_ws; (void)ws_size;
  const float* x = (const float*)d_in[0];
  float* out = (float*)d_out;
  const int B = in_sizes[0] / (S_LEN * NCH);   // 32

  const int nblk = (S_LEN / TILE_S) * B;       // 64 * 32 = 2048 (div by 8)
  dim3 grid(nblk);
  dim3 block(NCH, TY);                         // 512 threads = 8 waves
  hipLaunchKernelGGL(cwt_main, grid, block, 0, stream, x, out);
}

// Round 9
// 133.396 us; speedup vs baseline: 1.0205x; 1.0205x over previous
//
#include <hip/hip_runtime.h>
#include <math.h>

#define S_LEN  4096
#define NCH    64
#define BTILE  128          // s-rows per block
#define TY     8            // 8 waves, wave w owns s-subtile [BS0+16w, +16)
#define NCHUNK 26           // staged 8-row chunks: 208 rows = 32 halo + 128 + 48
#define CSTR   256          // ushorts per channel per plane (32 chunk slots x 8)

typedef __attribute__((ext_vector_type(8)))  short   short8v;
typedef __attribute__((ext_vector_type(8)))  __bf16  bf16x8;
typedef __attribute__((ext_vector_type(4)))  float   f32x4;

// ---------------------------------------------------------------------------
// Round-12: MFMA reformulation. Nine rounds of scheduling/occupancy/density
// changes inside the scalar-FMA structure all land cwt 46-53us vs ~23us
// memory floor (VALU floor ~13us, VALUBusy ~34%: distributed issue/latency
// friction no source reorder touched). This conv IS matmul-shaped:
// out[s,c] = sum_t w[t] x[s+t-off][c]  ==  banded-Toeplitz A (16xK, COMPILE-
// TIME constant -> constexpr-baked __constant__ fragment table, zero A loads)
// x dense B (K s-rows x 16 ch) via mfma_f32_16x16x32_bf16.
//   out6[s]=sum_{T<=61} w6[T]X[s+T-31]: A6p[i][k]=w6[32p+k-i-1], bases S0-32+32p
//   out3: A3p[i][k]=w3[32p+k-i], bases S0-16+32p;  out1: A1[i][k]=w1[k-i-2], S0-8
// All window bases = 0 mod 8 rows -> each B-frag is ONE aligned ds_read_b128
// from a transposed bf16 LDS tile [ch][chunk][8rows], chunk-slot XOR (ch&7)
// swizzled -> 2-way bank floor (b128 minimum). x split hi/lo bf16 (2-term:
// w_b*x_hi + w_b*x_lo = w_b*x exactly); only weight rounding adds error
// (~0.01-0.02 pred. vs threshold 0.103, base 0.0156). Compute 11.3us -> ~3us
// (MFMA pipe); kernel becomes pure streaming vs the 23us floor.
// Assumed gfx950 A/B lane maps (natural 2xK ext. of verified CDNA 16x16x16):
//   A[i][k]: i=lane&15, k=(lane>>4)*8+e;  B[k][j]: j=lane&15, k=(lane>>4)*8+e
//   C/D: col=lane&15, row=(lane>>4)*4+reg   [m89-verified]
// ---------------------------------------------------------------------------

// ---- constexpr weight construction (validated R4) --------------------------
constexpr double cexp_(double v) {            // v in [-25, 0]
  const double LN2 = 0.6931471805599453;
  double t = v / LN2;
  int k = (int)t;
  if (t < 0.0 && (double)k != t) --k;
  double r = v - (double)k * LN2;
  double term = 1.0, sum = 1.0;
  for (int n = 1; n <= 22; ++n) { term *= r / (double)n; sum += term; }
  while (k > 0) { sum *= 2.0; --k; }
  while (k < 0) { sum *= 0.5; ++k; }
  return sum;
}
constexpr double csqrt_(double a) {
  double y = a > 1.0 ? a : 1.0;
  for (int i = 0; i < 64; ++i) y = 0.5 * (y + a / y);
  return y;
}
struct Wt { float w6[62]; float w3[32]; float w1[12]; };
constexpr Wt make_weights() {
  Wt w{};
  double ip[1024] = {};
  const double delta = 10.0 / 1023.0;
  const double step  = (-5.0 + delta) + 5.0;
  const double cn    = csqrt_(csqrt_(1.5707963267948966));
  double s = 0.0;
  for (int i = 0; i < 1024; ++i) {
    const double xi  = (i == 1023) ? 5.0 : ((double)i * delta - 5.0);
    const double psi = (-2.0 * xi) * cexp_(-(xi * xi)) / cn;
    s += psi;
    ip[i] = s * step;
  }
  const int as_[3] = {6, 3, 1};
  const int lf_[3] = {61, 31, 11};
  for (int si = 0; si < 3; ++si) {
    const double denom = (double)as_[si] * step;
    const float  sqa   = (float)csqrt_((double)as_[si]);
    const int    lf    = lf_[si];
    for (int t = 0; t <= lf; ++t) {
      float km1 = 0.f, kt = 0.f;
      if (t >= 1)      km1 = (float)ip[(long)(((double)(t - 1)) / denom)];
      if (t <= lf - 1) kt  = (float)ip[(long)(((double)t) / denom)];
      const float val = -sqa * (km1 - kt);
      if (si == 0) w.w6[t] = val; else if (si == 1) w.w3[t] = val; else w.w1[t] = val;
    }
  }
  return w;
}

constexpr unsigned short bf16rne(float f) {
  const unsigned u = __builtin_bit_cast(unsigned, f);
  return (unsigned short)((u + 0x7FFFu + ((u >> 16) & 1u)) >> 16);
}

// ---- constexpr Toeplitz A-fragment table: 6 frags x 64 lanes x 8 bf16 ------
struct __align__(16) ATab { unsigned short v[6][64][8]; };
constexpr ATab make_atab() {
  ATab t{};
  constexpr Wt w = make_weights();
  for (int f = 0; f < 6; ++f)
    for (int l = 0; l < 64; ++l)
      for (int e = 0; e < 8; ++e) {
        const int i = l & 15, k = (l >> 4) * 8 + e;
        float val = 0.f;
        if (f < 3)      { const int d = 32 * f + k - i - 1;       if (d >= 0 && d < 62) val = w.w6[d]; }
        else if (f < 5) { const int d = 32 * (f - 3) + k - i;     if (d >= 0 && d < 32) val = w.w3[d]; }
        else            { const int d = k - i - 2;                if (d >= 0 && d < 12) val = w.w1[d]; }
        t.v[f][l][e] = bf16rne(val);
      }
  return t;
}
__constant__ ATab g_at = make_atab();

__global__ __launch_bounds__(512, 4)
void cwt_main(const float* __restrict__ x, float* __restrict__ out) {
  // two bf16 planes (hi, lo): [ch][chunk-slot][8 rows], chunk-slot = cidx^(ch&7)
  __shared__ __align__(16) unsigned short lds[2][NCH * CSTR];   // 65536 B -> 2 blk/CU

  const int c  = threadIdx.x;           // lane 0..63
  const int ty = threadIdx.y;           // wave 0..7

  // bijective XCD swizzle (nblk % 8 == 0)
  const int hw  = blockIdx.x;
  const int npx = gridDim.x >> 3;
  const int wg  = (hw & 7) * npx + (hw >> 3);
  const int sg  = wg & ((S_LEN / BTILE) - 1);
  const int b   = wg / (S_LEN / BTILE);
  const int BS0 = sg * BTILE;
  const int ROW0 = BS0 - 32;

  const float* __restrict__ xb = x + (size_t)b * S_LEN * NCH;

  // ---- stage: lane=channel scalar fp32 loads (256B/wave coalesced), split
  // to bf16 hi/lo, one ds_write_b128 per plane per 8-row chunk.
  #pragma unroll
  for (int q = 0; q < 4; ++q) {
    const int cidx = ty + 8 * q;
    if (cidx < NCHUNK) {
      const int r0 = ROW0 + cidx * 8;
      float v[8];
      #pragma unroll
      for (int r = 0; r < 8; ++r) {
        const int row = r0 + r;                       // wave-uniform guard
        v[r] = ((unsigned)row < (unsigned)S_LEN) ? xb[(size_t)row * NCH + c] : 0.f;
      }
      short8v ph, pl;
      #pragma unroll
      for (int r = 0; r < 8; ++r) {
        const unsigned u  = __builtin_bit_cast(unsigned, v[r]);
        const unsigned h  = (u + 0x7FFFu + ((u >> 16) & 1u)) >> 16;
        const float    fh = __builtin_bit_cast(float, h << 16);
        const float    rl = v[r] - fh;
        const unsigned ul = __builtin_bit_cast(unsigned, rl);
        const unsigned lo = (ul + 0x7FFFu + ((ul >> 16) & 1u)) >> 16;
        ph[r] = (short)h; pl[r] = (short)lo;
      }
      const int base = c * CSTR + ((cidx ^ (c & 7)) << 3);
      *(short8v*)&lds[0][base] = ph;
      *(short8v*)&lds[1][base] = pl;
    }
  }
  __syncthreads();

  // ---- per-wave MFMA over 4 channel-subtiles; A = constant frags ----------
  const int j  = c & 15;                 // output column within tile
  const int ck = c >> 4;                 // k-chunk group (8 rows)
  const int hh = c & 7;                  // == (channel)&7 for all jj (16|jj*16)

  const bf16x8 A60 = *(const bf16x8*)&g_at.v[0][c][0];
  const bf16x8 A61 = *(const bf16x8*)&g_at.v[1][c][0];
  const bf16x8 A62 = *(const bf16x8*)&g_at.v[2][c][0];
  const bf16x8 A30 = *(const bf16x8*)&g_at.v[3][c][0];
  const bf16x8 A31 = *(const bf16x8*)&g_at.v[4][c][0];
  const bf16x8 A10 = *(const bf16x8*)&g_at.v[5][c][0];

  const int cb0 = 2 * ty;                // wave's local window chunk base
  const size_t ob = (size_t)b * 3;
  const int srow = BS0 + 16 * ty + ck * 4;

  #pragma unroll
  for (int jj = 0; jj < 4; ++jj) {
    const int ch  = jj * 16 + j;
    const int chb = ch * CSTR;
    // B-frag: one aligned ds_read_b128 at [ch][(cb+ck)^hh][0..7]
    #define BRD(pl, cb) (*(const bf16x8*)&lds[pl][chb + ((((cb) + ck) ^ hh) << 3)])
    f32x4 s6 = {0.f, 0.f, 0.f, 0.f};
    f32x4 s3 = {0.f, 0.f, 0.f, 0.f};
    f32x4 s1 = {0.f, 0.f, 0.f, 0.f};
    s6 = __builtin_amdgcn_mfma_f32_16x16x32_bf16(A60, BRD(0, cb0 + 0), s6, 0, 0, 0);
    s6 = __builtin_amdgcn_mfma_f32_16x16x32_bf16(A60, BRD(1, cb0 + 0), s6, 0, 0, 0);
    s6 = __builtin_amdgcn_mfma_f32_16x16x32_bf16(A61, BRD(0, cb0 + 4), s6, 0, 0, 0);
    s6 = __builtin_amdgcn_mfma_f32_16x16x32_bf16(A61, BRD(1, cb0 + 4), s6, 0, 0, 0);
    s6 = __builtin_amdgcn_mfma_f32_16x16x32_bf16(A62, BRD(0, cb0 + 8), s6, 0, 0, 0);
    s6 = __builtin_amdgcn_mfma_f32_16x16x32_bf16(A62, BRD(1, cb0 + 8), s6, 0, 0, 0);
    s3 = __builtin_amdgcn_mfma_f32_16x16x32_bf16(A30, BRD(0, cb0 + 2), s3, 0, 0, 0);
    s3 = __builtin_amdgcn_mfma_f32_16x16x32_bf16(A30, BRD(1, cb0 + 2), s3, 0, 0, 0);
    s3 = __builtin_amdgcn_mfma_f32_16x16x32_bf16(A31, BRD(0, cb0 + 6), s3, 0, 0, 0);
    s3 = __builtin_amdgcn_mfma_f32_16x16x32_bf16(A31, BRD(1, cb0 + 6), s3, 0, 0, 0);
    s1 = __builtin_amdgcn_mfma_f32_16x16x32_bf16(A10, BRD(0, cb0 + 3), s1, 0, 0, 0);
    s1 = __builtin_amdgcn_mfma_f32_16x16x32_bf16(A10, BRD(1, cb0 + 3), s1, 0, 0, 0);
    #undef BRD

    // stores: C/D row = ck*4 + r, col = j; planes 0=s1, 1=s3, 2=s6
    float* o1p = out + ((ob + 0) * S_LEN + srow) * NCH + ch;
    float* o3p = out + ((ob + 1) * S_LEN + srow) * NCH + ch;
    float* o6p = out + ((ob + 2) * S_LEN + srow) * NCH + ch;
    #pragma unroll
    for (int r = 0; r < 4; ++r) {
      o1p[(size_t)r * NCH] = s1[r];
      o3p[(size_t)r * NCH] = s3[r];
      o6p[(size_t)r * NCH] = s6[r];
    }
  }
}

extern "C" void kernel_launch(void* const* d_in, const int* in_sizes, int n_in,
                              void* d_out, int out_size, void* d_ws, size_t ws_size,
                              hipStream_t stream) {
  (void)n_in; (void)out_size; (void)d_ws; (void)ws_size;
  const float* x = (const float*)d_in[0];
  float* out = (float*)d_out;
  const int B = in_sizes[0] / (S_LEN * NCH);   // 32

  const int nblk = (S_LEN / BTILE) * B;        // 32 * 32 = 1024 (div by 8)
  dim3 grid(nblk);
  dim3 block(NCH, TY);                         // 512 threads = 8 waves
  hipLaunchKernelGGL(cwt_main, grid, block, 0, stream, x, out);
}